// Round 15
// baseline (209.654 us; speedup 1.0000x reference)
//
#include <hip/hip_runtime.h>
#include <math.h>

#define FDIM 128
#define BKT_SHIFT 10

typedef short s16x8 __attribute__((ext_vector_type(8)));
typedef float f32x4 __attribute__((ext_vector_type(4)));

__device__ __forceinline__ ushort f2bf(float f) {
    union { float f; unsigned u; } v; v.f = f;
    unsigned u = v.u;
    unsigned r = (u + 0x7FFFu + ((u >> 16) & 1u)) >> 16;
    return (ushort)r;
}
__device__ __forceinline__ float bf2f(ushort b) {
    union { unsigned u; float f; } v; v.u = ((unsigned)b) << 16;
    return v.f;
}

// swizzled element index within a 128-elem row: chunk (k>>3) -> (k>>3)^(r&7)
__device__ __forceinline__ int swz_idx(int r, int k) {
    return (((k >> 3) ^ (r & 7)) << 3) | (k & 7);
}

// ---- setup: fused W0 weight + WTl(l>=1) + WTf + bucket hist + cursors, ONE kernel ----
__global__ __launch_bounds__(256) void k_setup(const float* __restrict__ w0,
                                               const float* __restrict__ Em,
                                               const float* __restrict__ b0,
                                               const float* __restrict__ gcn_W,
                                               const float* __restrict__ lt1_W,
                                               const int* __restrict__ ei,
                                               ushort* __restrict__ WTf0,
                                               ushort* __restrict__ WTl,
                                               ushort* __restrict__ WTf,
                                               int* __restrict__ phist,
                                               int* __restrict__ gcursor,
                                               int E, int L, int C, int nbkt,
                                               int binblocks) {
    __shared__ float smem[512];
    int b = blockIdx.x, tid = threadIdx.x;
    if (b < FDIM) {
        float* w0c  = smem;          // [128] W0[j][c]
        float* em   = smem + 128;    // [128]
        float* part = smem + 256;    // [2][128]
        int c = b;
        if (tid < FDIM) { w0c[tid] = gcn_W[tid * FDIM + c]; em[tid] = Em[tid]; }
        __syncthreads();
        int i = tid & 127, half = tid >> 7;
        float wi = w0[i];
        float acc = 0.f;
        int j0 = half * 64;
#pragma unroll 8
        for (int j = j0; j < j0 + 64; j++) {
            float v = wi * em[j] + b0[i * FDIM + j];
            acc += (v > 0.f ? v : 0.f) * w0c[j];
        }
        part[half * 128 + i] = acc;
        __syncthreads();
        if (half == 0) WTf0[c * FDIM + swz_idx(c, i)] = f2bf(part[i] + part[128 + i]);
        return;
    }
    b -= FDIM;
    if (b < (L - 1) * FDIM) {
        if (tid < FDIM) {
            int l = (b >> 7) + 1, c = b & 127, k = tid;
            WTl[(size_t)l * FDIM * FDIM + c * FDIM + swz_idx(c, k)] =
                f2bf(gcn_W[(size_t)l * FDIM * FDIM + k * FDIM + c]);
        }
        return;
    }
    b -= (L - 1) * FDIM;
    if (b < 48) {
        if (tid < FDIM) {
            int c = b, k = tid;
            WTf[c * FDIM + swz_idx(c, k)] = (c < C) ? f2bf(lt1_W[k * C + c]) : (ushort)0;
        }
        return;
    }
    b -= 48;
    if (b < binblocks) {
        int* lh = (int*)smem;
        if (tid < 64) lh[tid] = 0;
        __syncthreads();
        int base = b * 2048;
#pragma unroll
        for (int i = 0; i < 8; i++) {
            int e = base + i * 256 + tid;
            if (e < E) atomicAdd(&lh[ei[E + e] >> BKT_SHIFT], 1);
        }
        __syncthreads();
        if (tid < 64) phist[b * 64 + tid] = lh[tid];
        return;
    }
    if (tid < nbkt) gcursor[tid] = 0;
}

// ---------------- bin edges into buckets: bins[slot] = (dst<<16)|src -----------------
// bktstart computed per-block from phist (redundant, L2-resident) — no breduce kernel.
__global__ __launch_bounds__(256) void k_bin(const int* __restrict__ ei,
                                             const int* __restrict__ phist,
                                             int* __restrict__ gcursor,
                                             unsigned* __restrict__ bins,
                                             int E, int nblk) {
    __shared__ int part[4][64];
    __shared__ int bstart[64];
    __shared__ int lh[64];
    __shared__ int gb[64];
    int tid = threadIdx.x;
    // local bktstart: column sums of phist + 1-wave exclusive scan
    {
        int col = tid & 63, seg = tid >> 6;
        int s = 0;
        for (int r = seg; r < nblk; r += 4) s += phist[r * 64 + col];
        part[seg][col] = s;
    }
    if (tid < 64) lh[tid] = 0;
    __syncthreads();
    if (tid < 64) {
        int tot = part[0][tid] + part[1][tid] + part[2][tid] + part[3][tid];
        int sc = tot;
        for (int off = 1; off < 64; off <<= 1) {
            int t = __shfl_up(sc, off);
            if (tid >= off) sc += t;
        }
        bstart[tid] = sc - tot;
    }
    __syncthreads();

    unsigned rec[8];
    short loc[8];
    int base = blockIdx.x * 2048;
#pragma unroll
    for (int i = 0; i < 8; i++) {
        int e = base + i * 256 + tid;
        if (e < E) {
            unsigned s = (unsigned)ei[e], d = (unsigned)ei[E + e];
            rec[i] = (d << 16) | s;
            loc[i] = (short)atomicAdd(&lh[d >> BKT_SHIFT], 1);
        } else {
            rec[i] = 0xFFFFFFFFu;
        }
    }
    __syncthreads();
    if (tid < 64 && lh[tid] > 0) gb[tid] = atomicAdd(&gcursor[tid], lh[tid]);
    __syncthreads();
#pragma unroll
    for (int i = 0; i < 8; i++) {
        if (rec[i] != 0xFFFFFFFFu) {
            int bkt = rec[i] >> (16 + BKT_SHIFT);
            bins[bstart[bkt] + gb[bkt] + (int)loc[i]] = rec[i];
        }
    }
}

// ------ per-bucket CSR finalize: count + scan + rowptr/dis + scatter, all in LDS ------
// beg/end computed locally from phist (redundant) — no breduce kernel.
__global__ __launch_bounds__(1024) void k_bucket(const unsigned* __restrict__ bins,
                                                 const int* __restrict__ phist,
                                                 int* __restrict__ rowptr,
                                                 float* __restrict__ dis,
                                                 ushort* __restrict__ csr_s,
                                                 int N, int E, int nblk) {
    __shared__ int part[16][64];
    __shared__ int lh[1024];
    __shared__ int wsum[16];
    __shared__ int sBeg, sEnd;
    int tid = threadIdx.x;
    int bkt = blockIdx.x;
    // local bucket start/end
    {
        int col = tid & 63, seg = tid >> 6;
        int s = 0;
        for (int r = seg; r < nblk; r += 16) s += phist[r * 64 + col];
        part[seg][col] = s;
    }
    lh[tid] = 0;
    __syncthreads();
    if (tid < 64) {
        int tot = 0;
#pragma unroll
        for (int i = 0; i < 16; i++) tot += part[i][tid];
        int sc = tot;
        for (int off = 1; off < 64; off <<= 1) {
            int t = __shfl_up(sc, off);
            if (tid >= off) sc += t;
        }
        if (tid == bkt) { sBeg = sc - tot; sEnd = sc; }
    }
    __syncthreads();
    int beg = sBeg, end = sEnd;
    for (int i = beg + tid; i < end; i += 1024)
        atomicAdd(&lh[(bins[i] >> 16) & ((1 << BKT_SHIFT) - 1)], 1);
    __syncthreads();
    int deg = lh[tid];
    int lane = tid & 63, wv = tid >> 6;
    int incl = deg;
    for (int off = 1; off < 64; off <<= 1) {
        int t = __shfl_up(incl, off);
        if (lane >= off) incl += t;
    }
    if (lane == 63) wsum[wv] = incl;
    __syncthreads();
    int base = 0;
    for (int w = 0; w < wv; w++) base += wsum[w];
    int excl = base + incl - deg;
    int node0 = bkt << BKT_SHIFT;
    int node = node0 + tid;
    if (node < N) {
        rowptr[node] = beg + excl;
        dis[node] = rsqrtf((float)deg + 1.f);
    }
    __syncthreads();
    lh[tid] = excl;
    __syncthreads();
    for (int i = beg + tid; i < end; i += 1024) {
        unsigned rec = bins[i];
        int ln = (rec >> 16) & ((1 << BKT_SHIFT) - 1);
        int pos = atomicAdd(&lh[ln], 1);
        csr_s[beg + pos] = (ushort)(rec & 0xFFFFu);
    }
    if (bkt == 0 && tid == 0) rowptr[N] = E;
}

// ---- MFMA GEMM BM=64: C[n,128](bf16) = scale ⊙ (A[n,128] @ WT^T + bias) -----------
template <int A_FP32>
__global__ __launch_bounds__(256) void k_gemm_mfma(const void* __restrict__ Ain,
                                                   const ushort* __restrict__ WTs,
                                                   const float* __restrict__ bias,
                                                   const float* __restrict__ scale,
                                                   ushort* __restrict__ Cout, int n) {
    __shared__ ushort As[64 * FDIM];    // 16 KB
    __shared__ ushort Bs[FDIM * FDIM];  // 32 KB
    int tid = threadIdx.x;
    int wave = tid >> 6, lane = tid & 63;
    int row0 = blockIdx.x * 64;

    {
        const char* src = (const char*)WTs;
        char* dstb = (char*)Bs;
        int base = wave * 512;
#pragma unroll
        for (int i = 0; i < 8; i++) {
            int c0 = base + i * 64;
            __builtin_amdgcn_global_load_lds((const unsigned*)(src + (size_t)(c0 + lane) * 16),
                                             (unsigned*)(dstb + (size_t)c0 * 16), 16, 0, 0);
        }
    }
    if (A_FP32) {
        const float4* src = (const float4*)Ain;
        for (int t = tid; t < 1024; t += 256) {
            int r = t >> 4, c4 = t & 15;
            int row = row0 + r;
            float4 v0 = make_float4(0, 0, 0, 0), v1 = make_float4(0, 0, 0, 0);
            if (row < n) {
                v0 = src[row * 32 + c4 * 2];
                v1 = src[row * 32 + c4 * 2 + 1];
            }
            ushort4 b0, b1;
            b0.x = f2bf(v0.x); b0.y = f2bf(v0.y); b0.z = f2bf(v0.z); b0.w = f2bf(v0.w);
            b1.x = f2bf(v1.x); b1.y = f2bf(v1.y); b1.z = f2bf(v1.z); b1.w = f2bf(v1.w);
            int chs = (c4 ^ (r & 7)) * 8;
            *(ushort4*)&As[r * FDIM + chs] = b0;
            *(ushort4*)&As[r * FDIM + chs + 4] = b1;
        }
    } else {
        const char* src = (const char*)Ain;
        char* dsta = (char*)As;
        int base = wave * 256;
#pragma unroll
        for (int i = 0; i < 4; i++) {
            int c0 = base + i * 64;
            int c = c0 + lane;
            int r = c >> 4, chp = c & 15;
            size_t goff = ((size_t)(row0 + r) * 16 + (chp ^ (r & 7))) * 16;
            __builtin_amdgcn_global_load_lds((const unsigned*)(src + goff),
                                             (unsigned*)(dsta + (size_t)c0 * 16), 16, 0, 0);
        }
    }
    __syncthreads();

    int lr = lane & 15, lg = lane >> 4;
    f32x4 acc[8];
#pragma unroll
    for (int i = 0; i < 8; i++) acc[i] = (f32x4){0.f, 0.f, 0.f, 0.f};

#pragma unroll
    for (int k0 = 0; k0 < 4; k0++) {
        int kch = k0 * 4 + lg;
        int ar = wave * 16 + lr;
        s16x8 a = *(const s16x8*)&As[ar * FDIM + (kch ^ (ar & 7)) * 8];
#pragma unroll
        for (int ct = 0; ct < 8; ct++) {
            int bc = ct * 16 + lr;
            s16x8 b = *(const s16x8*)&Bs[bc * FDIM + (kch ^ (bc & 7)) * 8];
            acc[ct] = __builtin_amdgcn_mfma_f32_16x16x32_bf16(a, b, acc[ct], 0, 0, 0);
        }
    }
#pragma unroll
    for (int ct = 0; ct < 8; ct++) {
        int col = ct * 16 + lr;
        float bv = bias ? bias[col] : 0.f;
#pragma unroll
        for (int r = 0; r < 4; r++) {
            int row = row0 + wave * 16 + lg * 4 + r;
            if (row < n) {
                float sc = scale ? scale[row] : 1.f;
                Cout[(size_t)row * FDIM + col] = f2bf((acc[ct][r] + bv) * sc);
            } else {
                Cout[(size_t)row * FDIM + col] = 0;  // zero row for clamp gathers
            }
        }
    }
}

// ------- aggregate: h[node] = relu(dis[node] * Σ_{s∈{node}∪N(node)} hws[s]) ---------
__global__ __launch_bounds__(256) void k_aggregate(const ushort* __restrict__ hws,
                                                   const int* __restrict__ rowptr,
                                                   const ushort* __restrict__ csr_s,
                                                   const float* __restrict__ dis,
                                                   ushort* __restrict__ h, int n) {
    int node = blockIdx.x * 8 + threadIdx.y;
    if (node >= n) return;
    int q = threadIdx.x;
    const ushort4* hv = (const ushort4*)hws;
    float d = dis[node];
    ushort4 s4 = hv[node * 32 + q];
    float ax = bf2f(s4.x), ay = bf2f(s4.y), az = bf2f(s4.z), aw = bf2f(s4.w);
    int j = rowptr[node], end = rowptr[node + 1];
    for (; j < end; j += 8) {
        int idx[8];
#pragma unroll
        for (int b = 0; b < 8; b++) {
            int jj = j + b;
            idx[b] = (jj < end) ? (int)csr_s[jj] : n;
        }
        ushort4 v[8];
#pragma unroll
        for (int b = 0; b < 8; b++) v[b] = hv[idx[b] * 32 + q];
#pragma unroll
        for (int b = 0; b < 8; b++) {
            ax += bf2f(v[b].x); ay += bf2f(v[b].y);
            az += bf2f(v[b].z); aw += bf2f(v[b].w);
        }
    }
    ushort4 o;
    o.x = f2bf(fmaxf(ax * d, 0.f)); o.y = f2bf(fmaxf(ay * d, 0.f));
    o.z = f2bf(fmaxf(az * d, 0.f)); o.w = f2bf(fmaxf(aw * d, 0.f));
    ((ushort4*)h)[node * 32 + q] = o;
}

// ------- final: logits = h @ lt1_W + b via MFMA; out = log_softmax(logits) --------
__global__ __launch_bounds__(256) void k_final_mfma(const ushort* __restrict__ h,
                                                    const ushort* __restrict__ WTf,
                                                    const float* __restrict__ bias,
                                                    float* __restrict__ out, int n, int C) {
    __shared__ ushort As[64 * FDIM];   // 16 KB
    __shared__ ushort Bs[48 * FDIM];   // 12 KB
    int tid = threadIdx.x;
    int wave = tid >> 6, lane = tid & 63;
    int row0 = blockIdx.x * 64;

    {
        const char* src = (const char*)WTf;
        char* dstb = (char*)Bs;
        int base = wave * 192;
#pragma unroll
        for (int i = 0; i < 3; i++) {
            int c0 = base + i * 64;
            __builtin_amdgcn_global_load_lds((const unsigned*)(src + (size_t)(c0 + lane) * 16),
                                             (unsigned*)(dstb + (size_t)c0 * 16), 16, 0, 0);
        }
    }
    {
        const char* src = (const char*)h;
        char* dsta = (char*)As;
        int base = wave * 256;
#pragma unroll
        for (int i = 0; i < 4; i++) {
            int c0 = base + i * 64;
            int c = c0 + lane;
            int r = c >> 4, chp = c & 15;
            size_t goff = ((size_t)(row0 + r) * 16 + (chp ^ (r & 7))) * 16;
            __builtin_amdgcn_global_load_lds((const unsigned*)(src + goff),
                                             (unsigned*)(dsta + (size_t)c0 * 16), 16, 0, 0);
        }
    }
    __syncthreads();

    int lr = lane & 15, lg = lane >> 4;
    f32x4 acc[3];
#pragma unroll
    for (int i = 0; i < 3; i++) acc[i] = (f32x4){0.f, 0.f, 0.f, 0.f};

#pragma unroll
    for (int k0 = 0; k0 < 4; k0++) {
        int kch = k0 * 4 + lg;
        int ar = wave * 16 + lr;
        s16x8 a = *(const s16x8*)&As[ar * FDIM + (kch ^ (ar & 7)) * 8];
#pragma unroll
        for (int ct = 0; ct < 3; ct++) {
            int bc = ct * 16 + lr;
            s16x8 b = *(const s16x8*)&Bs[bc * FDIM + (kch ^ (bc & 7)) * 8];
            acc[ct] = __builtin_amdgcn_mfma_f32_16x16x32_bf16(a, b, acc[ct], 0, 0, 0);
        }
    }

    float bv[3];
#pragma unroll
    for (int ct = 0; ct < 3; ct++) {
        int col = ct * 16 + lr;
        bv[ct] = (col < C) ? bias[col] : 0.f;
    }
    bool v2ok = (32 + lr) < C;

#pragma unroll
    for (int r = 0; r < 4; r++) {
        float l0 = acc[0][r] + bv[0];
        float l1 = acc[1][r] + bv[1];
        float l2 = acc[2][r] + bv[2];
        float m = fmaxf(l0, l1);
        if (v2ok) m = fmaxf(m, l2);
#pragma unroll
        for (int off = 1; off < 16; off <<= 1) m = fmaxf(m, __shfl_xor(m, off));
        float e = __expf(l0 - m) + __expf(l1 - m) + (v2ok ? __expf(l2 - m) : 0.f);
#pragma unroll
        for (int off = 1; off < 16; off <<= 1) e += __shfl_xor(e, off);
        float lse = m + __logf(e);
        int row = row0 + wave * 16 + lg * 4 + r;
        if (row < n) {
            out[(size_t)row * C + lr] = l0 - lse;
            out[(size_t)row * C + 16 + lr] = l1 - lse;
            if (v2ok) out[(size_t)row * C + 32 + lr] = l2 - lse;
        }
    }
}

extern "C" void kernel_launch(void* const* d_in, const int* in_sizes, int n_in,
                              void* d_out, int out_size, void* d_ws, size_t ws_size,
                              hipStream_t stream) {
    const float* x      = (const float*)d_in[0];
    const int*   ei     = (const int*)d_in[1];
    const float* E_meta = (const float*)d_in[2];
    const float* w0     = (const float*)d_in[3];
    const float* b0     = (const float*)d_in[4];
    const float* gcn_W  = (const float*)d_in[5];
    const float* gcn_b  = (const float*)d_in[6];
    const float* lt1_W  = (const float*)d_in[7];
    const float* lt1_b  = (const float*)d_in[8];
    float* out = (float*)d_out;

    const int N = in_sizes[0] / FDIM;
    const int E = in_sizes[1] / 2;
    const int L = in_sizes[5] / (FDIM * FDIM);
    const int C = in_sizes[7] / FDIM;
    const int NBKT = (N + (1 << BKT_SHIFT) - 1) >> BKT_SHIFT;   // 49

    char* p = (char*)d_ws;
    auto alloc = [&](size_t bytes) {
        void* r = (void*)p;
        p += (bytes + 255) / 256 * 256;
        return r;
    };
    ushort*   WTf0    = (ushort*)alloc((size_t)FDIM * FDIM * 2);
    ushort*   WTl     = (ushort*)alloc((size_t)L * FDIM * FDIM * 2);
    ushort*   WTf     = (ushort*)alloc((size_t)48 * FDIM * 2);
    int*      rowptr  = (int*)alloc((size_t)(N + 1) * 4);
    float*    dis     = (float*)alloc((size_t)N * 4);
    int*      gcursor = (int*)alloc(64 * 4);
    const int binblocks = (E + 2047) / 2048;
    int*      phist   = (int*)alloc((size_t)binblocks * 64 * 4);
    unsigned* bins    = (unsigned*)alloc((size_t)E * 4);
    ushort*   csr_s   = (ushort*)alloc((size_t)E * 2);
    // h buffers padded +256 rows: unmasked async A-staging of tail blocks
    ushort*   hA      = (ushort*)alloc((size_t)(N + 256) * FDIM * 2);
    ushort*   hB      = (ushort*)alloc((size_t)(N + 256) * FDIM * 2);

    int setup_blocks = FDIM + (L - 1) * FDIM + 48 + binblocks + 1;
    k_setup<<<setup_blocks, 256, 0, stream>>>(w0, E_meta, b0, gcn_W, lt1_W, ei,
                                              WTf0, WTl, WTf, phist, gcursor,
                                              E, L, C, NBKT, binblocks);
    k_bin<<<binblocks, 256, 0, stream>>>(ei, phist, gcursor, bins, E, binblocks);
    k_bucket<<<NBKT, 1024, 0, stream>>>(bins, phist, rowptr, dis, csr_s, N, E, binblocks);

    int gemm_grid = (N + 63) / 64;
    dim3 ablk(32, 8);
    // layer 0 fused weight: hw0 = x @ (nw0 @ W0) + b0_gcn, dis-scaled
    k_gemm_mfma<1><<<gemm_grid, 256, 0, stream>>>(x, WTf0, gcn_b, dis, hB, N);
    k_aggregate<<<(N + 7) / 8, ablk, 0, stream>>>(hB, rowptr, csr_s, dis, hA, N);
    for (int l = 1; l < L; l++) {
        k_gemm_mfma<0><<<gemm_grid, 256, 0, stream>>>(hA, WTl + (size_t)l * FDIM * FDIM,
                                                      gcn_b + (size_t)l * FDIM, dis, hB, N);
        k_aggregate<<<(N + 7) / 8, ablk, 0, stream>>>(hB, rowptr, csr_s, dis, hA, N);
    }
    k_final_mfma<<<(N + 63) / 64, 256, 0, stream>>>(hA, WTf, lt1_b, out, N, C);
}

// Round 16
// 199.194 us; speedup vs baseline: 1.0525x; 1.0525x over previous
//
#include <hip/hip_runtime.h>
#include <math.h>

#define FDIM 128
#define BKT_SHIFT 10

typedef short s16x8 __attribute__((ext_vector_type(8)));
typedef float f32x4 __attribute__((ext_vector_type(4)));

__device__ __forceinline__ ushort f2bf(float f) {
    union { float f; unsigned u; } v; v.f = f;
    unsigned u = v.u;
    unsigned r = (u + 0x7FFFu + ((u >> 16) & 1u)) >> 16;
    return (ushort)r;
}
__device__ __forceinline__ float bf2f(ushort b) {
    union { unsigned u; float f; } v; v.u = ((unsigned)b) << 16;
    return v.f;
}

// swizzled element index within a 128-elem row: chunk (k>>3) -> (k>>3)^(r&7)
__device__ __forceinline__ int swz_idx(int r, int k) {
    return (((k >> 3) ^ (r & 7)) << 3) | (k & 7);
}

// ---- setup: fused W0 weight + WTl(l>=1) + WTf + bucket hist + cursors, ONE kernel ----
__global__ __launch_bounds__(256) void k_setup(const float* __restrict__ w0,
                                               const float* __restrict__ Em,
                                               const float* __restrict__ b0,
                                               const float* __restrict__ gcn_W,
                                               const float* __restrict__ lt1_W,
                                               const int* __restrict__ ei,
                                               ushort* __restrict__ WTf0,
                                               ushort* __restrict__ WTl,
                                               ushort* __restrict__ WTf,
                                               int* __restrict__ phist,
                                               int* __restrict__ gcursor,
                                               int E, int L, int C, int nbkt,
                                               int binblocks) {
    __shared__ float smem[512];
    int b = blockIdx.x, tid = threadIdx.x;
    if (b < FDIM) {
        float* w0c  = smem;          // [128] W0[j][c]
        float* em   = smem + 128;    // [128]
        float* part = smem + 256;    // [2][128]
        int c = b;
        if (tid < FDIM) { w0c[tid] = gcn_W[tid * FDIM + c]; em[tid] = Em[tid]; }
        __syncthreads();
        int i = tid & 127, half = tid >> 7;
        float wi = w0[i];
        float acc = 0.f;
        int j0 = half * 64;
#pragma unroll 8
        for (int j = j0; j < j0 + 64; j++) {
            float v = wi * em[j] + b0[i * FDIM + j];
            acc += (v > 0.f ? v : 0.f) * w0c[j];
        }
        part[half * 128 + i] = acc;
        __syncthreads();
        if (half == 0) WTf0[c * FDIM + swz_idx(c, i)] = f2bf(part[i] + part[128 + i]);
        return;
    }
    b -= FDIM;
    if (b < (L - 1) * FDIM) {
        if (tid < FDIM) {
            int l = (b >> 7) + 1, c = b & 127, k = tid;
            WTl[(size_t)l * FDIM * FDIM + c * FDIM + swz_idx(c, k)] =
                f2bf(gcn_W[(size_t)l * FDIM * FDIM + k * FDIM + c]);
        }
        return;
    }
    b -= (L - 1) * FDIM;
    if (b < 48) {
        if (tid < FDIM) {
            int c = b, k = tid;
            WTf[c * FDIM + swz_idx(c, k)] = (c < C) ? f2bf(lt1_W[k * C + c]) : (ushort)0;
        }
        return;
    }
    b -= 48;
    if (b < binblocks) {
        int* lh = (int*)smem;
        if (tid < 64) lh[tid] = 0;
        __syncthreads();
        int base = b * 2048;
#pragma unroll
        for (int i = 0; i < 8; i++) {
            int e = base + i * 256 + tid;
            if (e < E) atomicAdd(&lh[ei[E + e] >> BKT_SHIFT], 1);
        }
        __syncthreads();
        if (tid < 64) phist[b * 64 + tid] = lh[tid];
        return;
    }
    if (tid < nbkt) gcursor[tid] = 0;
}

// --------- reduce phist columns + exclusive scan -> bktstart (1 block) ----------
__global__ __launch_bounds__(1024) void k_breduce(const int* __restrict__ phist,
                                                  int* __restrict__ bktstart, int nblk) {
    __shared__ int part[16][64];
    int tid = threadIdx.x;
    int col = tid & 63, seg = tid >> 6;
    int s = 0;
    for (int r = seg; r < nblk; r += 16) s += phist[r * 64 + col];
    part[seg][col] = s;
    __syncthreads();
    if (tid < 64) {
        int tot = 0;
#pragma unroll
        for (int i = 0; i < 16; i++) tot += part[i][tid];
        int sc = tot;
        for (int off = 1; off < 64; off <<= 1) {
            int t = __shfl_up(sc, off);
            if (tid >= off) sc += t;
        }
        bktstart[tid] = sc - tot;
    }
}

// ---------------- bin edges into buckets: bins[slot] = (dst<<16)|src -----------------
__global__ __launch_bounds__(256) void k_bin(const int* __restrict__ ei,
                                             const int* __restrict__ bktstart,
                                             int* __restrict__ gcursor,
                                             unsigned* __restrict__ bins, int E) {
    __shared__ int lh[64];
    __shared__ int gb[64];
    int tid = threadIdx.x;
    if (tid < 64) lh[tid] = 0;
    __syncthreads();
    unsigned rec[8];
    short loc[8];
    int base = blockIdx.x * 2048;
#pragma unroll
    for (int i = 0; i < 8; i++) {
        int e = base + i * 256 + tid;
        if (e < E) {
            unsigned s = (unsigned)ei[e], d = (unsigned)ei[E + e];
            rec[i] = (d << 16) | s;
            loc[i] = (short)atomicAdd(&lh[d >> BKT_SHIFT], 1);
        } else {
            rec[i] = 0xFFFFFFFFu;
        }
    }
    __syncthreads();
    if (tid < 64 && lh[tid] > 0) gb[tid] = atomicAdd(&gcursor[tid], lh[tid]);
    __syncthreads();
#pragma unroll
    for (int i = 0; i < 8; i++) {
        if (rec[i] != 0xFFFFFFFFu) {
            int bkt = rec[i] >> (16 + BKT_SHIFT);
            bins[bktstart[bkt] + gb[bkt] + (int)loc[i]] = rec[i];
        }
    }
}

// ------ per-bucket CSR finalize: count + scan + rowptr/dis + scatter, all in LDS ------
__global__ __launch_bounds__(1024) void k_bucket(const unsigned* __restrict__ bins,
                                                 const int* __restrict__ bktstart,
                                                 int* __restrict__ rowptr,
                                                 float* __restrict__ dis,
                                                 ushort* __restrict__ csr_s,
                                                 int N, int E) {
    __shared__ int lh[1024];
    __shared__ int wsum[16];
    int tid = threadIdx.x;
    int bkt = blockIdx.x;
    int node0 = bkt << BKT_SHIFT;
    int beg = bktstart[bkt];
    int end = bktstart[bkt + 1];
    lh[tid] = 0;
    __syncthreads();
    for (int i = beg + tid; i < end; i += 1024)
        atomicAdd(&lh[(bins[i] >> 16) & ((1 << BKT_SHIFT) - 1)], 1);
    __syncthreads();
    int deg = lh[tid];
    int lane = tid & 63, wv = tid >> 6;
    int incl = deg;
    for (int off = 1; off < 64; off <<= 1) {
        int t = __shfl_up(incl, off);
        if (lane >= off) incl += t;
    }
    if (lane == 63) wsum[wv] = incl;
    __syncthreads();
    int base = 0;
    for (int w = 0; w < wv; w++) base += wsum[w];
    int excl = base + incl - deg;
    int node = node0 + tid;
    if (node < N) {
        rowptr[node] = beg + excl;
        dis[node] = rsqrtf((float)deg + 1.f);
    }
    __syncthreads();
    lh[tid] = excl;
    __syncthreads();
    for (int i = beg + tid; i < end; i += 1024) {
        unsigned rec = bins[i];
        int ln = (rec >> 16) & ((1 << BKT_SHIFT) - 1);
        int pos = atomicAdd(&lh[ln], 1);
        csr_s[beg + pos] = (ushort)(rec & 0xFFFFu);
    }
    if (bkt == 0 && tid == 0) rowptr[N] = E;
}

// ---- MFMA GEMM BM=64: C[n,128](bf16) = scale ⊙ (A[n,128] @ WT^T + bias) -----------
template <int A_FP32>
__global__ __launch_bounds__(256) void k_gemm_mfma(const void* __restrict__ Ain,
                                                   const ushort* __restrict__ WTs,
                                                   const float* __restrict__ bias,
                                                   const float* __restrict__ scale,
                                                   ushort* __restrict__ Cout, int n) {
    __shared__ ushort As[64 * FDIM];    // 16 KB
    __shared__ ushort Bs[FDIM * FDIM];  // 32 KB
    int tid = threadIdx.x;
    int wave = tid >> 6, lane = tid & 63;
    int row0 = blockIdx.x * 64;

    {
        const char* src = (const char*)WTs;
        char* dstb = (char*)Bs;
        int base = wave * 512;
#pragma unroll
        for (int i = 0; i < 8; i++) {
            int c0 = base + i * 64;
            __builtin_amdgcn_global_load_lds((const unsigned*)(src + (size_t)(c0 + lane) * 16),
                                             (unsigned*)(dstb + (size_t)c0 * 16), 16, 0, 0);
        }
    }
    if (A_FP32) {
        const float4* src = (const float4*)Ain;
        for (int t = tid; t < 1024; t += 256) {
            int r = t >> 4, c4 = t & 15;
            int row = row0 + r;
            float4 v0 = make_float4(0, 0, 0, 0), v1 = make_float4(0, 0, 0, 0);
            if (row < n) {
                v0 = src[row * 32 + c4 * 2];
                v1 = src[row * 32 + c4 * 2 + 1];
            }
            ushort4 b0, b1;
            b0.x = f2bf(v0.x); b0.y = f2bf(v0.y); b0.z = f2bf(v0.z); b0.w = f2bf(v0.w);
            b1.x = f2bf(v1.x); b1.y = f2bf(v1.y); b1.z = f2bf(v1.z); b1.w = f2bf(v1.w);
            int chs = (c4 ^ (r & 7)) * 8;
            *(ushort4*)&As[r * FDIM + chs] = b0;
            *(ushort4*)&As[r * FDIM + chs + 4] = b1;
        }
    } else {
        const char* src = (const char*)Ain;
        char* dsta = (char*)As;
        int base = wave * 256;
#pragma unroll
        for (int i = 0; i < 4; i++) {
            int c0 = base + i * 64;
            int c = c0 + lane;
            int r = c >> 4, chp = c & 15;
            size_t goff = ((size_t)(row0 + r) * 16 + (chp ^ (r & 7))) * 16;
            __builtin_amdgcn_global_load_lds((const unsigned*)(src + goff),
                                             (unsigned*)(dsta + (size_t)c0 * 16), 16, 0, 0);
        }
    }
    __syncthreads();

    int lr = lane & 15, lg = lane >> 4;
    f32x4 acc[8];
#pragma unroll
    for (int i = 0; i < 8; i++) acc[i] = (f32x4){0.f, 0.f, 0.f, 0.f};

#pragma unroll
    for (int k0 = 0; k0 < 4; k0++) {
        int kch = k0 * 4 + lg;
        int ar = wave * 16 + lr;
        s16x8 a = *(const s16x8*)&As[ar * FDIM + (kch ^ (ar & 7)) * 8];
#pragma unroll
        for (int ct = 0; ct < 8; ct++) {
            int bc = ct * 16 + lr;
            s16x8 b = *(const s16x8*)&Bs[bc * FDIM + (kch ^ (bc & 7)) * 8];
            acc[ct] = __builtin_amdgcn_mfma_f32_16x16x32_bf16(a, b, acc[ct], 0, 0, 0);
        }
    }
#pragma unroll
    for (int ct = 0; ct < 8; ct++) {
        int col = ct * 16 + lr;
        float bv = bias ? bias[col] : 0.f;
#pragma unroll
        for (int r = 0; r < 4; r++) {
            int row = row0 + wave * 16 + lg * 4 + r;
            if (row < n) {
                float sc = scale ? scale[row] : 1.f;
                Cout[(size_t)row * FDIM + col] = f2bf((acc[ct][r] + bv) * sc);
            } else {
                Cout[(size_t)row * FDIM + col] = 0;  // zero row for clamp gathers
            }
        }
    }
}

// ------- aggregate: h[node] = relu(dis[node] * Σ_{s∈{node}∪N(node)} hws[s]) ---------
__global__ __launch_bounds__(256) void k_aggregate(const ushort* __restrict__ hws,
                                                   const int* __restrict__ rowptr,
                                                   const ushort* __restrict__ csr_s,
                                                   const float* __restrict__ dis,
                                                   ushort* __restrict__ h, int n) {
    int node = blockIdx.x * 8 + threadIdx.y;
    if (node >= n) return;
    int q = threadIdx.x;
    const ushort4* hv = (const ushort4*)hws;
    float d = dis[node];
    ushort4 s4 = hv[node * 32 + q];
    float ax = bf2f(s4.x), ay = bf2f(s4.y), az = bf2f(s4.z), aw = bf2f(s4.w);
    int j = rowptr[node], end = rowptr[node + 1];
    for (; j < end; j += 8) {
        int idx[8];
#pragma unroll
        for (int b = 0; b < 8; b++) {
            int jj = j + b;
            idx[b] = (jj < end) ? (int)csr_s[jj] : n;
        }
        ushort4 v[8];
#pragma unroll
        for (int b = 0; b < 8; b++) v[b] = hv[idx[b] * 32 + q];
#pragma unroll
        for (int b = 0; b < 8; b++) {
            ax += bf2f(v[b].x); ay += bf2f(v[b].y);
            az += bf2f(v[b].z); aw += bf2f(v[b].w);
        }
    }
    ushort4 o;
    o.x = f2bf(fmaxf(ax * d, 0.f)); o.y = f2bf(fmaxf(ay * d, 0.f));
    o.z = f2bf(fmaxf(az * d, 0.f)); o.w = f2bf(fmaxf(aw * d, 0.f));
    ((ushort4*)h)[node * 32 + q] = o;
}

// ------- final: logits = h @ lt1_W + b via MFMA; out = log_softmax(logits) --------
__global__ __launch_bounds__(256) void k_final_mfma(const ushort* __restrict__ h,
                                                    const ushort* __restrict__ WTf,
                                                    const float* __restrict__ bias,
                                                    float* __restrict__ out, int n, int C) {
    __shared__ ushort As[64 * FDIM];   // 16 KB
    __shared__ ushort Bs[48 * FDIM];   // 12 KB
    int tid = threadIdx.x;
    int wave = tid >> 6, lane = tid & 63;
    int row0 = blockIdx.x * 64;

    {
        const char* src = (const char*)WTf;
        char* dstb = (char*)Bs;
        int base = wave * 192;
#pragma unroll
        for (int i = 0; i < 3; i++) {
            int c0 = base + i * 64;
            __builtin_amdgcn_global_load_lds((const unsigned*)(src + (size_t)(c0 + lane) * 16),
                                             (unsigned*)(dstb + (size_t)c0 * 16), 16, 0, 0);
        }
    }
    {
        const char* src = (const char*)h;
        char* dsta = (char*)As;
        int base = wave * 256;
#pragma unroll
        for (int i = 0; i < 4; i++) {
            int c0 = base + i * 64;
            int c = c0 + lane;
            int r = c >> 4, chp = c & 15;
            size_t goff = ((size_t)(row0 + r) * 16 + (chp ^ (r & 7))) * 16;
            __builtin_amdgcn_global_load_lds((const unsigned*)(src + goff),
                                             (unsigned*)(dsta + (size_t)c0 * 16), 16, 0, 0);
        }
    }
    __syncthreads();

    int lr = lane & 15, lg = lane >> 4;
    f32x4 acc[3];
#pragma unroll
    for (int i = 0; i < 3; i++) acc[i] = (f32x4){0.f, 0.f, 0.f, 0.f};

#pragma unroll
    for (int k0 = 0; k0 < 4; k0++) {
        int kch = k0 * 4 + lg;
        int ar = wave * 16 + lr;
        s16x8 a = *(const s16x8*)&As[ar * FDIM + (kch ^ (ar & 7)) * 8];
#pragma unroll
        for (int ct = 0; ct < 3; ct++) {
            int bc = ct * 16 + lr;
            s16x8 b = *(const s16x8*)&Bs[bc * FDIM + (kch ^ (bc & 7)) * 8];
            acc[ct] = __builtin_amdgcn_mfma_f32_16x16x32_bf16(a, b, acc[ct], 0, 0, 0);
        }
    }

    float bv[3];
#pragma unroll
    for (int ct = 0; ct < 3; ct++) {
        int col = ct * 16 + lr;
        bv[ct] = (col < C) ? bias[col] : 0.f;
    }
    bool v2ok = (32 + lr) < C;

#pragma unroll
    for (int r = 0; r < 4; r++) {
        float l0 = acc[0][r] + bv[0];
        float l1 = acc[1][r] + bv[1];
        float l2 = acc[2][r] + bv[2];
        float m = fmaxf(l0, l1);
        if (v2ok) m = fmaxf(m, l2);
#pragma unroll
        for (int off = 1; off < 16; off <<= 1) m = fmaxf(m, __shfl_xor(m, off));
        float e = __expf(l0 - m) + __expf(l1 - m) + (v2ok ? __expf(l2 - m) : 0.f);
#pragma unroll
        for (int off = 1; off < 16; off <<= 1) e += __shfl_xor(e, off);
        float lse = m + __logf(e);
        int row = row0 + wave * 16 + lg * 4 + r;
        if (row < n) {
            out[(size_t)row * C + lr] = l0 - lse;
            out[(size_t)row * C + 16 + lr] = l1 - lse;
            if (v2ok) out[(size_t)row * C + 32 + lr] = l2 - lse;
        }
    }
}

extern "C" void kernel_launch(void* const* d_in, const int* in_sizes, int n_in,
                              void* d_out, int out_size, void* d_ws, size_t ws_size,
                              hipStream_t stream) {
    const float* x      = (const float*)d_in[0];
    const int*   ei     = (const int*)d_in[1];
    const float* E_meta = (const float*)d_in[2];
    const float* w0     = (const float*)d_in[3];
    const float* b0     = (const float*)d_in[4];
    const float* gcn_W  = (const float*)d_in[5];
    const float* gcn_b  = (const float*)d_in[6];
    const float* lt1_W  = (const float*)d_in[7];
    const float* lt1_b  = (const float*)d_in[8];
    float* out = (float*)d_out;

    const int N = in_sizes[0] / FDIM;
    const int E = in_sizes[1] / 2;
    const int L = in_sizes[5] / (FDIM * FDIM);
    const int C = in_sizes[7] / FDIM;
    const int NBKT = (N + (1 << BKT_SHIFT) - 1) >> BKT_SHIFT;   // 49

    char* p = (char*)d_ws;
    auto alloc = [&](size_t bytes) {
        void* r = (void*)p;
        p += (bytes + 255) / 256 * 256;
        return r;
    };
    ushort*   WTf0    = (ushort*)alloc((size_t)FDIM * FDIM * 2);
    ushort*   WTl     = (ushort*)alloc((size_t)L * FDIM * FDIM * 2);
    ushort*   WTf     = (ushort*)alloc((size_t)48 * FDIM * 2);
    int*      rowptr  = (int*)alloc((size_t)(N + 1) * 4);
    float*    dis     = (float*)alloc((size_t)N * 4);
    int*      bktstart= (int*)alloc(64 * 4);
    int*      gcursor = (int*)alloc(64 * 4);
    const int binblocks = (E + 2047) / 2048;
    int*      phist   = (int*)alloc((size_t)binblocks * 64 * 4);
    unsigned* bins    = (unsigned*)alloc((size_t)E * 4);
    ushort*   csr_s   = (ushort*)alloc((size_t)E * 2);
    // h buffers padded +256 rows: unmasked async A-staging of tail blocks
    ushort*   hA      = (ushort*)alloc((size_t)(N + 256) * FDIM * 2);
    ushort*   hB      = (ushort*)alloc((size_t)(N + 256) * FDIM * 2);

    int setup_blocks = FDIM + (L - 1) * FDIM + 48 + binblocks + 1;
    k_setup<<<setup_blocks, 256, 0, stream>>>(w0, E_meta, b0, gcn_W, lt1_W, ei,
                                              WTf0, WTl, WTf, phist, gcursor,
                                              E, L, C, NBKT, binblocks);
    k_breduce<<<1, 1024, 0, stream>>>(phist, bktstart, binblocks);
    k_bin<<<binblocks, 256, 0, stream>>>(ei, bktstart, gcursor, bins, E);
    k_bucket<<<NBKT, 1024, 0, stream>>>(bins, bktstart, rowptr, dis, csr_s, N, E);

    int gemm_grid = (N + 63) / 64;
    dim3 ablk(32, 8);
    // layer 0 fused weight: hw0 = x @ (nw0 @ W0) + b0_gcn, dis-scaled
    k_gemm_mfma<1><<<gemm_grid, 256, 0, stream>>>(x, WTf0, gcn_b, dis, hB, N);
    k_aggregate<<<(N + 7) / 8, ablk, 0, stream>>>(hB, rowptr, csr_s, dis, hA, N);
    for (int l = 1; l < L; l++) {
        k_gemm_mfma<0><<<gemm_grid, 256, 0, stream>>>(hA, WTl + (size_t)l * FDIM * FDIM,
                                                      gcn_b + (size_t)l * FDIM, dis, hB, N);
        k_aggregate<<<(N + 7) / 8, ablk, 0, stream>>>(hB, rowptr, csr_s, dis, hA, N);
    }
    k_final_mfma<<<(N + 63) / 64, 256, 0, stream>>>(hA, WTf, lt1_b, out, N, C);
}